// Round 3
// baseline (543.842 us; speedup 1.0000x reference)
//
#include <hip/hip_runtime.h>
#include <stdint.h>

typedef float f32x4 __attribute__((ext_vector_type(4)));

#define FP8_MAX_V 448.0f

// Pack 4 floats -> 4 OCP e4m3fn bytes, RNE, after reference-matching clip.
__device__ __forceinline__ uint32_t pack4_fp8(float a, float b, float c, float d) {
    a = fminf(fmaxf(a, -FP8_MAX_V), FP8_MAX_V);
    b = fminf(fmaxf(b, -FP8_MAX_V), FP8_MAX_V);
    c = fminf(fmaxf(c, -FP8_MAX_V), FP8_MAX_V);
    d = fminf(fmaxf(d, -FP8_MAX_V), FP8_MAX_V);
    int v = 0;
    v = __builtin_amdgcn_cvt_pk_fp8_f32(a, b, v, false);  // bytes 0,1
    v = __builtin_amdgcn_cvt_pk_fp8_f32(c, d, v, true);   // bytes 2,3
    return (uint32_t)v;
}

__global__ void quant_fp8_kernel(const float* __restrict__ in,
                                 uint32_t* __restrict__ out,
                                 const float* __restrict__ scale_ptr,
                                 long long n4) {
    const float s = scale_ptr[0];
    long long i = (long long)blockIdx.x * blockDim.x + threadIdx.x;
    const long long stride = (long long)gridDim.x * blockDim.x;
    const float4* in4 = (const float4*)in;
    for (; i < n4; i += stride) {
        float4 v = in4[i];
        out[i] = pack4_fp8(v.x / s, v.y / s, v.z / s, v.w / s);
    }
}

// m201-style phase-pipelined fp8 GEMM: C = (qA . qB^T) * outscale + bias
// BM=256, BN=128, BK=64 B. Ring-4 LDS slots of 24 KiB (A 16K + B 8K) = 96 KiB.
// 8 waves = 4(M) x 2(N); per-wave 64x64 out via mfma_f32_16x16x32_fp8_fp8.
// 2 phases per K-tile, 16 MFMA per phase between raw barriers; prefetch
// distance 3 tiles; counted s_waitcnt vmcnt(6) once per tile (never 0).
// LDS swizzle at 16-B granularity: chunk' = chunk ^ ((row>>1)&3), applied on
// the global SOURCE (global_load_lds dest is linear) and on the ds_read col.
// 16-row fragments make this reach the b64 bank floor (32-row frags cannot).
__global__ __launch_bounds__(512, 2) void gemm_fp8_kernel(
    const uint8_t* __restrict__ qA,   // [M][K] fp8
    const uint8_t* __restrict__ qB,   // [N][K] fp8
    const float* __restrict__ bias,   // [N]
    const float* __restrict__ s_in_p,
    const float* __restrict__ s_w_p,
    float* __restrict__ C,            // [M][N] fp32
    int M, int N, int K) {
    extern __shared__ uint8_t lds[];  // 4 * 24576 = 98304 B

    const int tid = threadIdx.x;
    const int w   = tid >> 6;    // wave 0..7
    const int l   = tid & 63;
    const int wr  = w >> 1;      // 0..3 -> A rows [wr*64, +64)
    const int wc  = w & 1;       // 0..1 -> B rows [wc*64, +64)
    const int lr  = l & 15;      // fragment row
    const int lg  = l >> 4;      // k-group 0..3
    const int fl  = (lr >> 1) & 3;
    const int h8  = (lg & 1) << 3;
    const int cg0 = lg >> 1;     // chunk(ksub) = ksub*2 + cg0

    // XCD-bijective swizzle (nwg = 1792, divisible by 8)
    const int cpx = (int)gridDim.x >> 3;
    const int swz = ((int)blockIdx.x & 7) * cpx + ((int)blockIdx.x >> 3);
    const int bm  = (swz & 15) << 8;   // M/256 = 16 tiles
    const int bn  = (swz >> 4) << 7;   // N/128 = 112 tiles

    const float outscale = s_in_p[0] * s_w_p[0];
    const int NT = K >> 6;             // 64 K-tiles

    // Slot-relative swizzled read offsets (ksub = 0,1); +mi*1024/+ni*1024 later.
    int aOff[2], bOff[2];
#pragma unroll
    for (int k = 0; k < 2; ++k) {
        const int chunk = ((k * 2 + cg0) ^ fl) << 4;
        aOff[k] = (wr * 64 + lr) * 64 + chunk + h8;
        bOff[k] = 16384 + (wc * 64 + lr) * 64 + chunk + h8;
    }

    f32x4 acc[4][4];
#pragma unroll
    for (int mi = 0; mi < 4; ++mi)
#pragma unroll
        for (int ni = 0; ni < 4; ++ni)
            acc[mi][ni] = (f32x4){0.f, 0.f, 0.f, 0.f};

    // Staging: thread t covers row = t>>2 (128 rows / 8 KiB issue), 16-B chunk
    // t&3; source chunk pre-swizzled with f(row) = (row>>1)&3 (row mod 8
    // invariant across the j*128 second A issue).
    const int strow  = tid >> 2;
    const int schunk = (((tid & 3) ^ ((strow >> 1) & 3)) << 4);
    const uint8_t* sA = qA + (size_t)(bm + strow) * K + schunk;
    const uint8_t* sB = qB + (size_t)(bn + strow) * K + schunk;
    const int dstw = w << 10;   // wave-uniform piece; HW adds lane*16

#define STAGE_A(SL, KB) do { \
    __builtin_amdgcn_global_load_lds( \
        (const __attribute__((address_space(1))) void*)(sA + (KB)), \
        (__attribute__((address_space(3))) void*)(lds + (SL) * 24576 + dstw), 16, 0, 0); \
    __builtin_amdgcn_global_load_lds( \
        (const __attribute__((address_space(1))) void*)(sA + (size_t)128 * K + (KB)), \
        (__attribute__((address_space(3))) void*)(lds + (SL) * 24576 + 8192 + dstw), 16, 0, 0); \
} while (0)
#define STAGE_B(SL, KB) do { \
    __builtin_amdgcn_global_load_lds( \
        (const __attribute__((address_space(1))) void*)(sB + (KB)), \
        (__attribute__((address_space(3))) void*)(lds + (SL) * 24576 + 16384 + dstw), 16, 0, 0); \
} while (0)

    // Prologue: stage tiles 0,1,2 (3 loads each), wait oldest tile, barrier.
    STAGE_A(0, 0);   STAGE_B(0, 0);
    STAGE_A(1, 64);  STAGE_B(1, 64);
    STAGE_A(2, 128); STAGE_B(2, 128);
    asm volatile("s_waitcnt vmcnt(6)" ::: "memory");
    __builtin_amdgcn_s_barrier();

    long a[4][2], b[2][2];
    for (int T = 0; T < NT; ++T) {
        const uint8_t* sbase = lds + (T & 3) * 24576;
        const int Tp  = T + 3;
        const int kbp = (Tp < NT ? Tp : 0) << 6;  // clamp: writes a dead slot
        const int slp = Tp & 3;

        // ---------- phase 0: all A frags + B ni=0,1; MFMA quadrant ni 0-1 ----
        STAGE_A(slp, kbp);
#pragma unroll
        for (int mi = 0; mi < 4; ++mi)
#pragma unroll
            for (int k = 0; k < 2; ++k)
                a[mi][k] = *(const long*)(sbase + aOff[k] + mi * 1024);
#pragma unroll
        for (int ni = 0; ni < 2; ++ni)
#pragma unroll
            for (int k = 0; k < 2; ++k)
                b[ni][k] = *(const long*)(sbase + bOff[k] + ni * 1024);
        __builtin_amdgcn_s_barrier();
        asm volatile("s_waitcnt lgkmcnt(0)" ::: "memory");
        __builtin_amdgcn_sched_barrier(0);
        __builtin_amdgcn_s_setprio(1);
#pragma unroll
        for (int k = 0; k < 2; ++k)
#pragma unroll
            for (int mi = 0; mi < 4; ++mi)
#pragma unroll
                for (int ni = 0; ni < 2; ++ni)
                    acc[mi][ni] = __builtin_amdgcn_mfma_f32_16x16x32_fp8_fp8(
                        a[mi][k], b[ni][k], acc[mi][ni], 0, 0, 0);
        __builtin_amdgcn_s_setprio(0);
        __builtin_amdgcn_s_barrier();

        // ---------- phase 1: B ni=2,3; MFMA quadrant ni 2-3 ----
        STAGE_B(slp, kbp);
#pragma unroll
        for (int ni = 0; ni < 2; ++ni)
#pragma unroll
            for (int k = 0; k < 2; ++k)
                b[ni][k] = *(const long*)(sbase + bOff[k] + (ni + 2) * 1024);
        __builtin_amdgcn_s_barrier();
        asm volatile("s_waitcnt lgkmcnt(0)" ::: "memory");
        __builtin_amdgcn_sched_barrier(0);
        __builtin_amdgcn_s_setprio(1);
#pragma unroll
        for (int k = 0; k < 2; ++k)
#pragma unroll
            for (int mi = 0; mi < 4; ++mi)
#pragma unroll
                for (int ni = 0; ni < 2; ++ni)
                    acc[mi][ni + 2] = __builtin_amdgcn_mfma_f32_16x16x32_fp8_fp8(
                        a[mi][k], b[ni][k], acc[mi][ni + 2], 0, 0, 0);
        __builtin_amdgcn_s_setprio(0);
        // Keep tiles T+2,T+3 (6 loads) in flight; oldest 3 (tile T+1) land.
        asm volatile("s_waitcnt vmcnt(6)" ::: "memory");
        __builtin_amdgcn_s_barrier();
    }

    // Epilogue. 16x16 C/D layout: col = lane&15, row = (lane>>4)*4 + reg.
    const int crow0 = bm + wr * 64 + (lg << 2);
    const int ccol0 = bn + wc * 64 + lr;
#pragma unroll
    for (int ni = 0; ni < 4; ++ni) {
        const int col = ccol0 + ni * 16;
        const float bv = bias[col];
#pragma unroll
        for (int mi = 0; mi < 4; ++mi) {
            const int row = crow0 + mi * 16;
#pragma unroll
            for (int r = 0; r < 4; ++r)
                C[(size_t)(row + r) * N + col] = acc[mi][ni][r] * outscale + bv;
        }
    }
#undef STAGE_A
#undef STAGE_B
}

extern "C" void kernel_launch(void* const* d_in, const int* in_sizes, int n_in,
                              void* d_out, int out_size, void* d_ws, size_t ws_size,
                              hipStream_t stream) {
    const float* x    = (const float*)d_in[0];
    const float* wt   = (const float*)d_in[1];
    const float* bias = (const float*)d_in[2];
    const float* s_in = (const float*)d_in[3];
    const float* s_w  = (const float*)d_in[4];
    float* out = (float*)d_out;

    const long long xe = in_sizes[0];            // M*K
    const long long we = in_sizes[1];            // N*K
    const int N = in_sizes[2];
    const int K = (int)(we / N);
    const int M = (int)(xe / K);

    uint8_t* qx = (uint8_t*)d_ws;                // M*K fp8
    uint8_t* qw = qx + xe;                       // N*K fp8

    quant_fp8_kernel<<<2048, 256, 0, stream>>>(x,  (uint32_t*)qx, s_in, xe >> 2);
    quant_fp8_kernel<<<2048, 256, 0, stream>>>(wt, (uint32_t*)qw, s_w,  we >> 2);

    dim3 grid((N / 128) * (M / 256));            // 112*16 = 1792 = 7 per CU
    gemm_fp8_kernel<<<grid, 512, 98304, stream>>>(qx, qw, bias, s_in, s_w, out,
                                                  M, N, K);
}

// Round 4
// 396.478 us; speedup vs baseline: 1.3717x; 1.3717x over previous
//
#include <hip/hip_runtime.h>
#include <stdint.h>

typedef float f32x4 __attribute__((ext_vector_type(4)));
typedef int   i32x8 __attribute__((ext_vector_type(8)));
typedef long  i64x2 __attribute__((ext_vector_type(2)));

#define FP8_MAX_V 448.0f

// Pack 4 floats -> 4 OCP e4m3fn bytes, RNE, after reference-matching clip.
__device__ __forceinline__ uint32_t pack4_fp8(float a, float b, float c, float d) {
    a = fminf(fmaxf(a, -FP8_MAX_V), FP8_MAX_V);
    b = fminf(fmaxf(b, -FP8_MAX_V), FP8_MAX_V);
    c = fminf(fmaxf(c, -FP8_MAX_V), FP8_MAX_V);
    d = fminf(fmaxf(d, -FP8_MAX_V), FP8_MAX_V);
    int v = 0;
    v = __builtin_amdgcn_cvt_pk_fp8_f32(a, b, v, false);  // bytes 0,1
    v = __builtin_amdgcn_cvt_pk_fp8_f32(c, d, v, true);   // bytes 2,3
    return (uint32_t)v;
}

__global__ void quant_fp8_kernel(const float* __restrict__ in,
                                 uint32_t* __restrict__ out,
                                 const float* __restrict__ scale_ptr,
                                 long long n4) {
    const float s = scale_ptr[0];
    long long i = (long long)blockIdx.x * blockDim.x + threadIdx.x;
    const long long stride = (long long)gridDim.x * blockDim.x;
    const float4* in4 = (const float4*)in;
    for (; i < n4; i += stride) {
        float4 v = in4[i];
        out[i] = pack4_fp8(v.x / s, v.y / s, v.z / s, v.w / s);
    }
}

// MX-scaled fp8 GEMM (m148 ladder step): C = (qA . qB^T) * outscale + bias.
// Round-1 (m97) structure: 128x128 tile, BK=128 bytes, 4 waves (2x2), each
// wave 64x64 out as 4x4 16x16 fragments, single-buffered LDS, 2 barriers per
// K-tile. MFMA = mfma_scale_f32_16x16x128_f8f6f4 with E8M0 scales = 127
// (=2^0=1.0) -> numerically identical to plain fp8 GEMM, 2x the MFMA rate.
// LDS swizzle: 16B slot = chunk ^ (row&7), applied on the global SOURCE
// (global_load_lds dest is linear) and on the ds_read address (rule #21).
// A-fragment per lane: row = l&15, k = (l>>4)*32 + j (32 contiguous bytes,
// extrapolating the round-1-verified 16x16x32 layout by 4x K).
__global__ __launch_bounds__(256, 3) void gemm_mxfp8_kernel(
    const uint8_t* __restrict__ qA,   // [M][K] fp8
    const uint8_t* __restrict__ qB,   // [N][K] fp8
    const float* __restrict__ bias,   // [N]
    const float* __restrict__ s_in_p,
    const float* __restrict__ s_w_p,
    float* __restrict__ C,            // [M][N] fp32
    int M, int N, int K) {
    __shared__ uint8_t lsA[128 * 128];
    __shared__ uint8_t lsB[128 * 128];

    const int tid = threadIdx.x;
    const int w   = tid >> 6;   // wave 0..3
    const int l   = tid & 63;
    const int wr  = w >> 1;     // rows [wr*64, +64)
    const int wc  = w & 1;      // cols [wc*64, +64)
    const int lr  = l & 15;     // fragment row
    const int lg  = l >> 4;     // k-group: k in [lg*32, +32)
    const int lsw = lr & 7;     // read/stage XOR swizzle key

    // XCD-bijective block swizzle: grid = 3584 = 8 * 448.
    const int cpx = (int)gridDim.x >> 3;
    const int swz = ((int)blockIdx.x & 7) * cpx + ((int)blockIdx.x >> 3);
    const int bm  = (swz & 31) << 7;   // M/128 = 32 tiles (pow2)
    const int bn  = (swz >> 5) << 7;   // N/128 = 112 tiles

    const float outscale = s_in_p[0] * s_w_p[0];
    const int NT = K >> 7;             // 32 K-tiles of 128 bytes

    // Two b128 reads per 32-B fragment: slots (2lg)^lsw and (2lg+1)^lsw.
    const int off0 = (((lg << 1) ^ lsw) << 4);
    const int off1 = off0 ^ 16;

    f32x4 acc[4][4];
#pragma unroll
    for (int mi = 0; mi < 4; ++mi)
#pragma unroll
        for (int ni = 0; ni < 4; ++ni)
            acc[mi][ni] = (f32x4){0.f, 0.f, 0.f, 0.f};

    // Staging: thread t covers row = t>>3 (32 rows / 4 KiB per issue),
    // 16-B chunk t&7, source chunk pre-swizzled with (row&7). Rows of
    // later issues differ by 32 -> (row&7) invariant.
    const int srow = tid >> 3;
    const int sc   = (((tid & 7) ^ (srow & 7)) << 4);
    const uint8_t* sA = qA + (size_t)(bm + srow) * K + sc;
    const uint8_t* sB = qB + (size_t)(bn + srow) * K + sc;
    const int dstw = w << 10;   // wave-uniform LDS piece; HW adds lane*16

    union frag { i32x8 v; i64x2 h[2]; };

    for (int kt = 0; kt < NT; ++kt) {
        const int kb = kt << 7;
#pragma unroll
        for (int i = 0; i < 4; ++i) {
            __builtin_amdgcn_global_load_lds(
                (const __attribute__((address_space(1))) void*)(sA + (size_t)(i * 32) * K + kb),
                (__attribute__((address_space(3))) void*)(lsA + i * 4096 + dstw), 16, 0, 0);
        }
#pragma unroll
        for (int i = 0; i < 4; ++i) {
            __builtin_amdgcn_global_load_lds(
                (const __attribute__((address_space(1))) void*)(sB + (size_t)(i * 32) * K + kb),
                (__attribute__((address_space(3))) void*)(lsB + i * 4096 + dstw), 16, 0, 0);
        }
        __syncthreads();

        i32x8 a[4], b[4];
#pragma unroll
        for (int mi = 0; mi < 4; ++mi) {
            const uint8_t* base = lsA + ((wr * 64 + mi * 16 + lr) << 7);
            frag u;
            u.h[0] = *(const i64x2*)(base + off0);
            u.h[1] = *(const i64x2*)(base + off1);
            a[mi] = u.v;
        }
#pragma unroll
        for (int ni = 0; ni < 4; ++ni) {
            const uint8_t* base = lsB + ((wc * 64 + ni * 16 + lr) << 7);
            frag u;
            u.h[0] = *(const i64x2*)(base + off0);
            u.h[1] = *(const i64x2*)(base + off1);
            b[ni] = u.v;
        }
#pragma unroll
        for (int mi = 0; mi < 4; ++mi)
#pragma unroll
            for (int ni = 0; ni < 4; ++ni)
                acc[mi][ni] = __builtin_amdgcn_mfma_scale_f32_16x16x128_f8f6f4(
                    a[mi], b[ni], acc[mi][ni],
                    0, 0,          // cbsz=fp8(e4m3), blgp=fp8(e4m3)
                    0, 127,        // scale_a: opsel 0, E8M0 127 = 1.0
                    0, 127);       // scale_b: opsel 0, E8M0 127 = 1.0
        __syncthreads();
    }

    // Epilogue. 16x16 C/D layout: col = lane&15, row = (lane>>4)*4 + reg.
    const int crow0 = bm + wr * 64 + (lg << 2);
    const int ccol0 = bn + wc * 64 + lr;
#pragma unroll
    for (int ni = 0; ni < 4; ++ni) {
        const int col = ccol0 + ni * 16;
        const float bv = bias[col];
#pragma unroll
        for (int mi = 0; mi < 4; ++mi) {
            const int row = crow0 + mi * 16;
#pragma unroll
            for (int r = 0; r < 4; ++r)
                C[(size_t)(row + r) * N + col] = acc[mi][ni][r] * outscale + bv;
        }
    }
}

extern "C" void kernel_launch(void* const* d_in, const int* in_sizes, int n_in,
                              void* d_out, int out_size, void* d_ws, size_t ws_size,
                              hipStream_t stream) {
    const float* x    = (const float*)d_in[0];
    const float* wt   = (const float*)d_in[1];
    const float* bias = (const float*)d_in[2];
    const float* s_in = (const float*)d_in[3];
    const float* s_w  = (const float*)d_in[4];
    float* out = (float*)d_out;

    const long long xe = in_sizes[0];            // M*K
    const long long we = in_sizes[1];            // N*K
    const int N = in_sizes[2];
    const int K = (int)(we / N);
    const int M = (int)(xe / K);

    uint8_t* qx = (uint8_t*)d_ws;                // M*K fp8
    uint8_t* qw = qx + xe;                       // N*K fp8

    quant_fp8_kernel<<<2048, 256, 0, stream>>>(x,  (uint32_t*)qx, s_in, xe >> 2);
    quant_fp8_kernel<<<2048, 256, 0, stream>>>(wt, (uint32_t*)qw, s_w,  we >> 2);

    dim3 grid((M / 128) * (N / 128));            // 32*112 = 3584 (8 | 3584)
    gemm_mxfp8_kernel<<<grid, 256, 0, stream>>>(qx, qw, bias, s_in, s_w, out,
                                                M, N, K);
}